// Round 9
// baseline (2545.613 us; speedup 1.0000x reference)
//
#include <hip/hip_runtime.h>
#include <hip/hip_bf16.h>
#include <math.h>

#define B_    8
#define C_    192
#define H_    112
#define W_    112
#define HD    56
#define WDIM  56
#define NPTS  3136      // 56*56
#define KNN   9
#define O_    192
#define NTOT  (B_*C_*NPTS)          // 4,816,896 pooled elems
#define OUT_TOT (B_*O_*H_*W_)       // 19,267,584

// ---------------- K0: W prep: Wd_t[c][o] = W[o][c]-W[o][c+192]; W2_t[c][o]=W[o][c+192]
__global__ void k_wprep(const float* __restrict__ Wc,
                        float* __restrict__ Wd_t, float* __restrict__ W2_t) {
    int idx = blockIdx.x * 256 + threadIdx.x;
    if (idx >= C_ * O_) return;
    int o = idx / C_, c = idx % C_;          // read coalesced over c
    float w1 = Wc[o * 384 + c];
    float w2 = Wc[o * 384 + 192 + c];
    Wd_t[c * O_ + o] = w1 - w2;
    W2_t[c * O_ + o] = w2;
}

// ---------------- K1: 2x2 avg pool -> xd (B,C,N)
__global__ void k_pool(const float* __restrict__ x, float* __restrict__ xd) {
    int idx = blockIdx.x * 256 + threadIdx.x;
    if (idx >= NTOT) return;
    int wd = idx % WDIM; int t = idx / WDIM;
    int hd = t % HD;     int bc = t / HD;
    const float* p = x + ((size_t)bc * H_ + 2 * hd) * W_ + 2 * wd;
    xd[idx] = 0.25f * ((p[0] + p[1]) + (p[W_] + p[W_ + 1]));
}

// ---------------- K2: transpose (B,C,N) -> (B,N,C)
__global__ void k_transpose(const float* __restrict__ xd, float* __restrict__ xt) {
    __shared__ float tile[32][33];
    int bb = blockIdx.z;
    int n0 = blockIdx.x * 32, c0 = blockIdx.y * 32;
    int tx = threadIdx.x, ty = threadIdx.y;   // 32 x 8
    const float* src = xd + (size_t)bb * C_ * NPTS;
    float* dst = xt + (size_t)bb * NPTS * C_;
    #pragma unroll
    for (int j = 0; j < 32; j += 8)
        tile[ty + j][tx] = src[(size_t)(c0 + ty + j) * NPTS + n0 + tx];
    __syncthreads();
    #pragma unroll
    for (int j = 0; j < 32; j += 8)
        dst[(size_t)(n0 + ty + j) * C_ + c0 + tx] = tile[tx][ty + j];
}

// ---------------- K3: sq[b][n] = sum_c xt^2
__global__ void k_sq(const float* __restrict__ xt, float* __restrict__ sq) {
    __shared__ float part[64][4];
    int t = threadIdx.x; int r = t & 63, s = t >> 6;
    int bb = blockIdx.y; int n = blockIdx.x * 64 + r;
    const float* row = xt + ((size_t)bb * NPTS + n) * C_ + s * 48;
    float acc = 0.f;
    #pragma unroll
    for (int c = 0; c < 48; c += 4) {
        float4 v4 = *reinterpret_cast<const float4*>(row + c);
        acc += v4.x * v4.x + v4.y * v4.y + v4.z * v4.z + v4.w * v4.w;
    }
    part[r][s] = acc;
    __syncthreads();
    if (t < 64)
        sq[(size_t)bb * NPTS + blockIdx.x * 64 + t] =
            (part[t][0] + part[t][1]) + (part[t][2] + part[t][3]);
}

// ---------------- K4: u = xt*(W1-W2)^T + b ; v = xt*W2^T   (32 n x 64 o per block)
__global__ __launch_bounds__(256) void k_uv(const float* __restrict__ xt,
                     const float* __restrict__ Wd_t, const float* __restrict__ W2_t,
                     const float* __restrict__ bc,
                     float* __restrict__ u, float* __restrict__ v) {
    __shared__ float xs[32][192];
    int t = threadIdx.x;
    int bb = blockIdx.z, n0 = blockIdx.y * 32;
    int o = blockIdx.x * 64 + (t & 63);
    int w = t >> 6;                      // wave id 0..3
    #pragma unroll
    for (int k = 0; k < 24; ++k) {
        int e = k * 256 + t; int nl = e / 192, c = e % 192;
        xs[nl][c] = xt[((size_t)bb * NPTS + n0 + nl) * C_ + c];
    }
    __syncthreads();
    float au[8], av[8];
    #pragma unroll
    for (int j = 0; j < 8; ++j) { au[j] = 0.f; av[j] = 0.f; }
    for (int c = 0; c < 192; ++c) {
        float w1 = Wd_t[c * O_ + o];
        float w2 = W2_t[c * O_ + o];
        #pragma unroll
        for (int j = 0; j < 8; ++j) {
            float xv = xs[w + 4 * j][c];   // wave-uniform -> LDS broadcast
            au[j] += xv * w1;
            av[j] += xv * w2;
        }
    }
    float bias = bc[o];
    #pragma unroll
    for (int j = 0; j < 8; ++j) {
        int n = n0 + w + 4 * j;
        u[((size_t)bb * NPTS + n) * O_ + o] = au[j] + bias;
        v[((size_t)bb * NPTS + n) * O_ + o] = av[j];
    }
}

// ---------------- K5: kNN top-9 per row.  32 rows x 8 m-slots per 256-thr block.
#define LESSP(da, ia, db, ib) (((da) < (db)) || (((da) == (db)) && ((ia) < (ib))))

__global__ __launch_bounds__(256) void k_knn(const float* __restrict__ xt,
                                             const float* __restrict__ sq,
                                             int* __restrict__ nn) {
    __shared__ float Atr[192 * 33];      // transposed A tile [c][r], conflict-free b32 reads
    int t = threadIdx.x;
    int r = t & 31, s = t >> 5;          // r: row 0..31, s: m-slot 0..7
    int bb = blockIdx.y; int n0 = blockIdx.x * 32;
    const float* xb = xt + (size_t)bb * NPTS * C_;
    #pragma unroll
    for (int k = 0; k < 24; ++k) {
        int e = k * 256 + t; int rr = e / 192, c = e % 192;
        Atr[c * 33 + rr] = xb[(size_t)(n0 + rr) * C_ + c];
    }
    __syncthreads();

    float d9[9]; int i9[9];
    #pragma unroll
    for (int k = 0; k < 9; ++k) { d9[k] = INFINITY; i9[k] = 0x7fffffff; }
    const float* sqb = sq + (size_t)bb * NPTS;

    for (int g = 0; g < 98; ++g) {
        int m0 = g * 32 + s * 4;
        const float* b0 = xb + (size_t)m0 * C_;
        float acc0 = 0.f, acc1 = 0.f, acc2 = 0.f, acc3 = 0.f;
        #pragma unroll 8
        for (int c4 = 0; c4 < 48; ++c4) {
            int c = c4 * 4;
            float4 bv0 = *reinterpret_cast<const float4*>(b0 + c);
            float4 bv1 = *reinterpret_cast<const float4*>(b0 + 192 + c);
            float4 bv2 = *reinterpret_cast<const float4*>(b0 + 384 + c);
            float4 bv3 = *reinterpret_cast<const float4*>(b0 + 576 + c);
            float a0 = Atr[(c + 0) * 33 + r];
            float a1 = Atr[(c + 1) * 33 + r];
            float a2 = Atr[(c + 2) * 33 + r];
            float a3 = Atr[(c + 3) * 33 + r];
            acc0 += a0 * bv0.x + a1 * bv0.y + a2 * bv0.z + a3 * bv0.w;
            acc1 += a0 * bv1.x + a1 * bv1.y + a2 * bv1.z + a3 * bv1.w;
            acc2 += a0 * bv2.x + a1 * bv2.y + a2 * bv2.z + a3 * bv2.w;
            acc3 += a0 * bv3.x + a1 * bv3.y + a2 * bv3.z + a3 * bv3.w;
        }
        float4 sqm = *reinterpret_cast<const float4*>(sqb + m0);
        float sc[4] = { sqm.x - 2.f * acc0, sqm.y - 2.f * acc1,
                        sqm.z - 2.f * acc2, sqm.w - 2.f * acc3 };
        #pragma unroll
        for (int i = 0; i < 4; ++i) {
            float d = sc[i]; int m = m0 + i;
            if (LESSP(d, m, d9[8], i9[8])) {   // bubble-insert, compile-time indices only
                float pd = d; int pi = m;
                #pragma unroll
                for (int k = 0; k < 9; ++k) {
                    bool cnd = LESSP(pd, pi, d9[k], i9[k]);
                    float td = d9[k]; int ti = i9[k];
                    d9[k] = cnd ? pd : td;  i9[k] = cnd ? pi : ti;
                    pd = cnd ? td : pd;     pi = cnd ? ti : pi;
                }
            }
        }
    }
    __syncthreads();                     // done reading Atr -> alias for merge
    float* md = Atr;                     // [32][8][9] floats
    int*   mi = reinterpret_cast<int*>(&Atr[2304]);
    #pragma unroll
    for (int k = 0; k < 9; ++k) {
        md[(r * 8 + s) * 9 + k] = d9[k];
        mi[(r * 8 + s) * 9 + k] = i9[k];
    }
    __syncthreads();
    if (t < 32) {
        int n = n0 + t;
        int p[8];
        #pragma unroll
        for (int s2 = 0; s2 < 8; ++s2) p[s2] = 0;
        for (int k = 0; k < 9; ++k) {
            float bd = INFINITY; int bi = 0x7fffffff; int bs = -1;
            #pragma unroll
            for (int s2 = 0; s2 < 8; ++s2) {
                float dv = md[(t * 8 + s2) * 9 + p[s2]];
                int   iv = mi[(t * 8 + s2) * 9 + p[s2]];
                if (LESSP(dv, iv, bd, bi)) { bd = dv; bi = iv; bs = s2; }
            }
            nn[((size_t)bb * NPTS + n) * KNN + k] = bi;
            #pragma unroll
            for (int s2 = 0; s2 < 8; ++s2) if (s2 == bs) p[s2]++;
        }
    }
}

// ---------------- K6: h = u[n]+v[m], gelu, max over k; write (B,O,N) via LDS transpose
__global__ __launch_bounds__(256) void k_gmax(const float* __restrict__ u,
                      const float* __restrict__ v, const int* __restrict__ nn,
                      float* __restrict__ os) {
    __shared__ float st[192 * 33];
    __shared__ int   sidx[32 * KNN];
    int t = threadIdx.x;
    int bb = blockIdx.y, n0 = blockIdx.x * 32;
    for (int e = t; e < 32 * KNN; e += 256)
        sidx[e] = nn[((size_t)bb * NPTS + n0) * KNN + e];
    __syncthreads();
    const float* vb = v + (size_t)bb * NPTS * O_;
    #pragma unroll 2
    for (int wv = 0; wv < 24; ++wv) {
        int e = wv * 256 + t; int nl = e / 192, o = e % 192;
        float uo = u[((size_t)bb * NPTS + n0 + nl) * O_ + o];
        float best = -INFINITY;
        #pragma unroll
        for (int k = 0; k < KNN; ++k) {
            int m = sidx[nl * KNN + k];
            float h = uo + vb[(size_t)m * O_ + o];
            float gel = 0.5f * h * (1.0f + erff(h * 0.70710678118654752f));
            best = fmaxf(best, gel);
        }
        st[o * 33 + nl] = best;
    }
    __syncthreads();
    float* ob = os + (size_t)bb * O_ * NPTS;
    #pragma unroll 2
    for (int wv = 0; wv < 24; ++wv) {
        int e = wv * 256 + t; int o = e / 32, nl = e % 32;
        ob[(size_t)o * NPTS + n0 + nl] = st[o * 33 + nl];
    }
}

// ---------------- K7: 2x bilinear upsample 56->112 (half-pixel, edge-renormalized)
__global__ void k_upsample(const float* __restrict__ os, float* __restrict__ out) {
    int idx = blockIdx.x * 256 + threadIdx.x;
    if (idx >= OUT_TOT) return;
    int j = idx % W_; int t2 = idx / W_;
    int i = t2 % H_;  int bo = t2 / H_;
    int i0, i1; float wi0, wi1;
    if (i & 1) { i0 = i >> 1; i1 = i0 + 1; wi0 = 0.75f; wi1 = 0.25f; }
    else       { i1 = i >> 1; i0 = i1 - 1; wi0 = 0.25f; wi1 = 0.75f; }
    i0 = max(i0, 0); i1 = min(i1, HD - 1);
    int j0, j1; float wj0, wj1;
    if (j & 1) { j0 = j >> 1; j1 = j0 + 1; wj0 = 0.75f; wj1 = 0.25f; }
    else       { j1 = j >> 1; j0 = j1 - 1; wj0 = 0.25f; wj1 = 0.75f; }
    j0 = max(j0, 0); j1 = min(j1, WDIM - 1);
    const float* base = os + (size_t)bo * NPTS;
    float v00 = base[i0 * WDIM + j0], v01 = base[i0 * WDIM + j1];
    float v10 = base[i1 * WDIM + j0], v11 = base[i1 * WDIM + j1];
    out[idx] = wi0 * (wj0 * v00 + wj1 * v01) + wi1 * (wj0 * v10 + wj1 * v11);
}

extern "C" void kernel_launch(void* const* d_in, const int* in_sizes, int n_in,
                              void* d_out, int out_size, void* d_ws, size_t ws_size,
                              hipStream_t stream) {
    const float* x  = (const float*)d_in[0];
    const float* Wc = (const float*)d_in[1];
    const float* bc = (const float*)d_in[2];
    float* out = (float*)d_out;

    char* ws = (char*)d_ws;
    const size_t SZ = (size_t)NTOT * 4;        // 19,267,584 B
    float* xd = (float*)(ws);                  // aliased later by os
    float* xt = (float*)(ws + SZ);
    float* u  = (float*)(ws + 2 * SZ);
    float* v  = (float*)(ws + 3 * SZ);
    float* sq = (float*)(ws + 4 * SZ);                       // 100,352 B
    float* Wd = (float*)(ws + 4 * SZ + 100352);              // 147,456 B
    float* W2 = (float*)(ws + 4 * SZ + 100352 + 147456);     // 147,456 B
    int*   nn = (int*)  (ws + 4 * SZ + 100352 + 2 * 147456); // 903,168 B
    float* os = xd;                            // reuse: xd dead after k_transpose

    k_wprep<<<dim3((C_ * O_ + 255) / 256), 256, 0, stream>>>(Wc, Wd, W2);
    k_pool<<<dim3(NTOT / 256), 256, 0, stream>>>(x, xd);
    k_transpose<<<dim3(NPTS / 32, C_ / 32, B_), dim3(32, 8), 0, stream>>>(xd, xt);
    k_sq<<<dim3(NPTS / 64, B_), 256, 0, stream>>>(xt, sq);
    k_uv<<<dim3(O_ / 64, NPTS / 32, B_), 256, 0, stream>>>(xt, Wd, W2, bc, u, v);
    k_knn<<<dim3(NPTS / 32, B_), 256, 0, stream>>>(xt, sq, nn);
    k_gmax<<<dim3(NPTS / 32, B_), 256, 0, stream>>>(u, v, nn, os);
    k_upsample<<<dim3(OUT_TOT / 256), 256, 0, stream>>>(os, out);
}

// Round 10
// 2443.036 us; speedup vs baseline: 1.0420x; 1.0420x over previous
//
#include <hip/hip_runtime.h>
#include <hip/hip_bf16.h>
#include <math.h>

#define B_    8
#define C_    192
#define H_    112
#define W_    112
#define HD    56
#define WDIM  56
#define NPTS  3136      // 56*56
#define KNN   9
#define O_    192
#define NTOT  (B_*C_*NPTS)          // 4,816,896 pooled elems
#define OUT_TOT (B_*O_*H_*W_)       // 19,267,584
#define MSPLIT 1792     // m-range split point: 1792 and 1344, both % 64 == 0

// ---------------- K0: W prep: Wd_t[c][o] = W[o][c]-W[o][c+192]; W2_t[c][o]=W[o][c+192]
__global__ void k_wprep(const float* __restrict__ Wc,
                        float* __restrict__ Wd_t, float* __restrict__ W2_t) {
    int idx = blockIdx.x * 256 + threadIdx.x;
    if (idx >= C_ * O_) return;
    int o = idx / C_, c = idx % C_;          // read coalesced over c
    float w1 = Wc[o * 384 + c];
    float w2 = Wc[o * 384 + 192 + c];
    Wd_t[c * O_ + o] = w1 - w2;
    W2_t[c * O_ + o] = w2;
}

// ---------------- K1: 2x2 avg pool -> xd (B,C,N)
__global__ void k_pool(const float* __restrict__ x, float* __restrict__ xd) {
    int idx = blockIdx.x * 256 + threadIdx.x;
    if (idx >= NTOT) return;
    int wd = idx % WDIM; int t = idx / WDIM;
    int hd = t % HD;     int bc = t / HD;
    const float* p = x + ((size_t)bc * H_ + 2 * hd) * W_ + 2 * wd;
    xd[idx] = 0.25f * ((p[0] + p[1]) + (p[W_] + p[W_ + 1]));
}

// ---------------- K2: transpose (B,C,N) -> (B,N,C)
__global__ void k_transpose(const float* __restrict__ xd, float* __restrict__ xt) {
    __shared__ float tile[32][33];
    int bb = blockIdx.z;
    int n0 = blockIdx.x * 32, c0 = blockIdx.y * 32;
    int tx = threadIdx.x, ty = threadIdx.y;   // 32 x 8
    const float* src = xd + (size_t)bb * C_ * NPTS;
    float* dst = xt + (size_t)bb * NPTS * C_;
    #pragma unroll
    for (int j = 0; j < 32; j += 8)
        tile[ty + j][tx] = src[(size_t)(c0 + ty + j) * NPTS + n0 + tx];
    __syncthreads();
    #pragma unroll
    for (int j = 0; j < 32; j += 8)
        dst[(size_t)(n0 + ty + j) * C_ + c0 + tx] = tile[tx][ty + j];
}

// ---------------- K3: sq[b][n] = sum_c xt^2
__global__ void k_sq(const float* __restrict__ xt, float* __restrict__ sq) {
    __shared__ float part[64][4];
    int t = threadIdx.x; int r = t & 63, s = t >> 6;
    int bb = blockIdx.y; int n = blockIdx.x * 64 + r;
    const float* row = xt + ((size_t)bb * NPTS + n) * C_ + s * 48;
    float acc = 0.f;
    #pragma unroll
    for (int c = 0; c < 48; c += 4) {
        float4 v4 = *reinterpret_cast<const float4*>(row + c);
        acc += v4.x * v4.x + v4.y * v4.y + v4.z * v4.z + v4.w * v4.w;
    }
    part[r][s] = acc;
    __syncthreads();
    if (t < 64)
        sq[(size_t)bb * NPTS + blockIdx.x * 64 + t] =
            (part[t][0] + part[t][1]) + (part[t][2] + part[t][3]);
}

// ---------------- K4: u = xt*(W1-W2)^T + b ; v = xt*W2^T   (32 n x 64 o per block)
__global__ __launch_bounds__(256) void k_uv(const float* __restrict__ xt,
                     const float* __restrict__ Wd_t, const float* __restrict__ W2_t,
                     const float* __restrict__ bc,
                     float* __restrict__ u, float* __restrict__ v) {
    __shared__ float xs[32][192];
    int t = threadIdx.x;
    int bb = blockIdx.z, n0 = blockIdx.y * 32;
    int o = blockIdx.x * 64 + (t & 63);
    int w = t >> 6;                      // wave id 0..3
    #pragma unroll
    for (int k = 0; k < 24; ++k) {
        int e = k * 256 + t; int nl = e / 192, c = e % 192;
        xs[nl][c] = xt[((size_t)bb * NPTS + n0 + nl) * C_ + c];
    }
    __syncthreads();
    float au[8], av[8];
    #pragma unroll
    for (int j = 0; j < 8; ++j) { au[j] = 0.f; av[j] = 0.f; }
    for (int c = 0; c < 192; ++c) {
        float w1 = Wd_t[c * O_ + o];
        float w2 = W2_t[c * O_ + o];
        #pragma unroll
        for (int j = 0; j < 8; ++j) {
            float xv = xs[w + 4 * j][c];   // wave-uniform -> LDS broadcast
            au[j] += xv * w1;
            av[j] += xv * w2;
        }
    }
    float bias = bc[o];
    #pragma unroll
    for (int j = 0; j < 8; ++j) {
        int n = n0 + w + 4 * j;
        u[((size_t)bb * NPTS + n) * O_ + o] = au[j] + bias;
        v[((size_t)bb * NPTS + n) * O_ + o] = av[j];
    }
}

// ---------------- K5: kNN partial top-9.  32 rows/block; 8 slots x 8 m = 64 m per g-iter.
// Grid x = 196: rb = x>>1 (row-block), half = x&1 (m-range half: [0,1792) / [1792,3136)).
// Writes per-(row,half) top-9 partial lists; k_knnmerge combines.
#define LESSP(da, ia, db, ib) (((da) < (db)) || (((da) == (db)) && ((ia) < (ib))))

__global__ __launch_bounds__(256) void k_knn(const float* __restrict__ xt,
                                             const float* __restrict__ sq,
                                             float* __restrict__ pd,
                                             int* __restrict__ pi) {
    __shared__ float Atr[192 * 33];      // transposed A tile [c][r], conflict-free b32 reads
    int t = threadIdx.x;
    int r = t & 31, s = t >> 5;          // r: row 0..31, s: m-slot 0..7
    int bb = blockIdx.y;
    int rb = blockIdx.x >> 1, half = blockIdx.x & 1;
    int n0 = rb * 32;
    const float* xb = xt + (size_t)bb * NPTS * C_;
    #pragma unroll
    for (int k = 0; k < 24; ++k) {
        int e = k * 256 + t; int rr = e / 192, c = e % 192;
        Atr[c * 33 + rr] = xb[(size_t)(n0 + rr) * C_ + c];
    }
    __syncthreads();

    float d9[9]; int i9[9];
    #pragma unroll
    for (int k = 0; k < 9; ++k) { d9[k] = INFINITY; i9[k] = 0x7fffffff; }
    const float* sqb = sq + (size_t)bb * NPTS;

    const int mstart = half ? MSPLIT : 0;
    const int gcnt   = half ? (NPTS - MSPLIT) / 64 : MSPLIT / 64;   // 21 : 28

    for (int g = 0; g < gcnt; ++g) {
        int m0 = mstart + g * 64 + s * 8;
        const float* b0 = xb + (size_t)m0 * C_;
        float acc[8];
        #pragma unroll
        for (int i = 0; i < 8; ++i) acc[i] = 0.f;
        #pragma unroll 2
        for (int c4 = 0; c4 < 48; ++c4) {
            int c = c4 * 4;
            float4 bv[8];
            #pragma unroll
            for (int i = 0; i < 8; ++i)
                bv[i] = *reinterpret_cast<const float4*>(b0 + i * C_ + c);
            float a0 = Atr[(c + 0) * 33 + r];
            float a1 = Atr[(c + 1) * 33 + r];
            float a2 = Atr[(c + 2) * 33 + r];
            float a3 = Atr[(c + 3) * 33 + r];
            #pragma unroll
            for (int i = 0; i < 8; ++i)
                acc[i] += a0 * bv[i].x + a1 * bv[i].y + a2 * bv[i].z + a3 * bv[i].w;
        }
        float4 sq0 = *reinterpret_cast<const float4*>(sqb + m0);
        float4 sq1 = *reinterpret_cast<const float4*>(sqb + m0 + 4);
        float sc[8] = { sq0.x - 2.f * acc[0], sq0.y - 2.f * acc[1],
                        sq0.z - 2.f * acc[2], sq0.w - 2.f * acc[3],
                        sq1.x - 2.f * acc[4], sq1.y - 2.f * acc[5],
                        sq1.z - 2.f * acc[6], sq1.w - 2.f * acc[7] };
        #pragma unroll
        for (int i = 0; i < 8; ++i) {
            float d = sc[i]; int m = m0 + i;
            if (LESSP(d, m, d9[8], i9[8])) {   // bubble-insert, compile-time indices only
                float pdv = d; int piv = m;
                #pragma unroll
                for (int k = 0; k < 9; ++k) {
                    bool cnd = LESSP(pdv, piv, d9[k], i9[k]);
                    float td = d9[k]; int ti = i9[k];
                    d9[k] = cnd ? pdv : td;  i9[k] = cnd ? piv : ti;
                    pdv = cnd ? td : pdv;    piv = cnd ? ti : piv;
                }
            }
        }
    }
    __syncthreads();                     // done reading Atr -> alias for merge
    float* md = Atr;                     // [32][8][9] floats
    int*   mi = reinterpret_cast<int*>(&Atr[2304]);
    #pragma unroll
    for (int k = 0; k < 9; ++k) {
        md[(r * 8 + s) * 9 + k] = d9[k];
        mi[(r * 8 + s) * 9 + k] = i9[k];
    }
    __syncthreads();
    if (t < 32) {
        int p[8];
        #pragma unroll
        for (int s2 = 0; s2 < 8; ++s2) p[s2] = 0;
        size_t base = ((size_t)(bb * NPTS + n0 + t) * 2 + half) * 9;
        for (int k = 0; k < 9; ++k) {
            float bd = INFINITY; int bi = 0x7fffffff; int bs = -1;
            #pragma unroll
            for (int s2 = 0; s2 < 8; ++s2) {
                float dv = md[(t * 8 + s2) * 9 + p[s2]];
                int   iv = mi[(t * 8 + s2) * 9 + p[s2]];
                if (LESSP(dv, iv, bd, bi)) { bd = dv; bi = iv; bs = s2; }
            }
            pd[base + k] = bd;
            pi[base + k] = bi;
            #pragma unroll
            for (int s2 = 0; s2 < 8; ++s2) if (s2 == bs) p[s2]++;
        }
    }
}

// ---------------- K5b: merge two per-half top-9 lists -> global top-9 indices
__global__ void k_knnmerge(const float* __restrict__ pd, const int* __restrict__ pi,
                           int* __restrict__ nn) {
    int row = blockIdx.x * 256 + threadIdx.x;
    if (row >= B_ * NPTS) return;
    const float* d0 = pd + (size_t)row * 18;   // [half0: 9][half1: 9], each sorted
    const int*   i0 = pi + (size_t)row * 18;
    int p0 = 0, p1 = 0;
    for (int k = 0; k < 9; ++k) {
        float da = d0[p0], db = d0[9 + p1];
        int   ia = i0[p0], ib = i0[9 + p1];
        bool a = LESSP(da, ia, db, ib);
        nn[(size_t)row * KNN + k] = a ? ia : ib;
        if (a) p0++; else p1++;
    }
}

// ---------------- K6: h = u[n]+v[m], gelu, max over k; write (B,O,N) via LDS transpose
__global__ __launch_bounds__(256) void k_gmax(const float* __restrict__ u,
                      const float* __restrict__ v, const int* __restrict__ nn,
                      float* __restrict__ os) {
    __shared__ float st[192 * 33];
    __shared__ int   sidx[32 * KNN];
    int t = threadIdx.x;
    int bb = blockIdx.y, n0 = blockIdx.x * 32;
    for (int e = t; e < 32 * KNN; e += 256)
        sidx[e] = nn[((size_t)bb * NPTS + n0) * KNN + e];
    __syncthreads();
    const float* vb = v + (size_t)bb * NPTS * O_;
    #pragma unroll 2
    for (int wv = 0; wv < 24; ++wv) {
        int e = wv * 256 + t; int nl = e / 192, o = e % 192;
        float uo = u[((size_t)bb * NPTS + n0 + nl) * O_ + o];
        float best = -INFINITY;
        #pragma unroll
        for (int k = 0; k < KNN; ++k) {
            int m = sidx[nl * KNN + k];
            float h = uo + vb[(size_t)m * O_ + o];
            float gel = 0.5f * h * (1.0f + erff(h * 0.70710678118654752f));
            best = fmaxf(best, gel);
        }
        st[o * 33 + nl] = best;
    }
    __syncthreads();
    float* ob = os + (size_t)bb * O_ * NPTS;
    #pragma unroll 2
    for (int wv = 0; wv < 24; ++wv) {
        int e = wv * 256 + t; int o = e / 32, nl = e % 32;
        ob[(size_t)o * NPTS + n0 + nl] = st[o * 33 + nl];
    }
}

// ---------------- K7: 2x bilinear upsample 56->112 (half-pixel, edge-renormalized)
__global__ void k_upsample(const float* __restrict__ os, float* __restrict__ out) {
    int idx = blockIdx.x * 256 + threadIdx.x;
    if (idx >= OUT_TOT) return;
    int j = idx % W_; int t2 = idx / W_;
    int i = t2 % H_;  int bo = t2 / H_;
    int i0, i1; float wi0, wi1;
    if (i & 1) { i0 = i >> 1; i1 = i0 + 1; wi0 = 0.75f; wi1 = 0.25f; }
    else       { i1 = i >> 1; i0 = i1 - 1; wi0 = 0.25f; wi1 = 0.75f; }
    i0 = max(i0, 0); i1 = min(i1, HD - 1);
    int j0, j1; float wj0, wj1;
    if (j & 1) { j0 = j >> 1; j1 = j0 + 1; wj0 = 0.75f; wj1 = 0.25f; }
    else       { j1 = j >> 1; j0 = j1 - 1; wj0 = 0.25f; wj1 = 0.75f; }
    j0 = max(j0, 0); j1 = min(j1, WDIM - 1);
    const float* base = os + (size_t)bo * NPTS;
    float v00 = base[i0 * WDIM + j0], v01 = base[i0 * WDIM + j1];
    float v10 = base[i1 * WDIM + j0], v11 = base[i1 * WDIM + j1];
    out[idx] = wi0 * (wj0 * v00 + wj1 * v01) + wi1 * (wj0 * v10 + wj1 * v11);
}

extern "C" void kernel_launch(void* const* d_in, const int* in_sizes, int n_in,
                              void* d_out, int out_size, void* d_ws, size_t ws_size,
                              hipStream_t stream) {
    const float* x  = (const float*)d_in[0];
    const float* Wc = (const float*)d_in[1];
    const float* bc = (const float*)d_in[2];
    float* out = (float*)d_out;

    char* ws = (char*)d_ws;
    const size_t SZ = (size_t)NTOT * 4;        // 19,267,584 B
    float* xd = (float*)(ws);                  // dead after k_transpose -> reused for pd/pi, then os
    float* xt = (float*)(ws + SZ);
    float* u  = (float*)(ws + 2 * SZ);
    float* v  = (float*)(ws + 3 * SZ);
    float* sq = (float*)(ws + 4 * SZ);                       // 100,352 B
    float* Wd = (float*)(ws + 4 * SZ + 100352);              // 147,456 B
    float* W2 = (float*)(ws + 4 * SZ + 100352 + 147456);     // 147,456 B
    int*   nn = (int*)  (ws + 4 * SZ + 100352 + 2 * 147456); // 903,168 B
    // partial top-9 lists live in the dead xd region (3.6 MB << SZ);
    // dead again before k_gmax writes os over the same region.
    float* pd = (float*)(ws);                                // 25088*18*4 = 1,806,336 B
    int*   pi = (int*)  (ws + 1806336);                      // 1,806,336 B
    float* os = xd;                            // reuse: pd/pi dead after k_knnmerge

    k_wprep<<<dim3((C_ * O_ + 255) / 256), 256, 0, stream>>>(Wc, Wd, W2);
    k_pool<<<dim3(NTOT / 256), 256, 0, stream>>>(x, xd);
    k_transpose<<<dim3(NPTS / 32, C_ / 32, B_), dim3(32, 8), 0, stream>>>(xd, xt);
    k_sq<<<dim3(NPTS / 64, B_), 256, 0, stream>>>(xt, sq);
    k_uv<<<dim3(O_ / 64, NPTS / 32, B_), 256, 0, stream>>>(xt, Wd, W2, bc, u, v);
    k_knn<<<dim3((NPTS / 32) * 2, B_), 256, 0, stream>>>(xt, sq, pd, pi);
    k_knnmerge<<<dim3((B_ * NPTS + 255) / 256), 256, 0, stream>>>(pd, pi, nn);
    k_gmax<<<dim3(NPTS / 32, B_), 256, 0, stream>>>(u, v, nn, os);
    k_upsample<<<dim3(OUT_TOT / 256), 256, 0, stream>>>(os, out);
}

// Round 11
// 1595.174 us; speedup vs baseline: 1.5958x; 1.5315x over previous
//
#include <hip/hip_runtime.h>
#include <hip/hip_bf16.h>
#include <math.h>

#define B_    8
#define C_    192
#define H_    112
#define W_    112
#define HD    56
#define WDIM  56
#define NPTS  3136      // 56*56 = 49*64
#define KNN   9
#define O_    192
#define NTOT  (B_*C_*NPTS)          // 4,816,896 pooled elems
#define OUT_TOT (B_*O_*H_*W_)       // 19,267,584
#define NCH   5         // m-chunks in k_knn grid (panels: 10,10,10,10,9 of 64 m)

// ---------------- K0: W prep: Wd_t[c][o] = W[o][c]-W[o][c+192]; W2_t[c][o]=W[o][c+192]
__global__ void k_wprep(const float* __restrict__ Wc,
                        float* __restrict__ Wd_t, float* __restrict__ W2_t) {
    int idx = blockIdx.x * 256 + threadIdx.x;
    if (idx >= C_ * O_) return;
    int o = idx / C_, c = idx % C_;          // read coalesced over c
    float w1 = Wc[o * 384 + c];
    float w2 = Wc[o * 384 + 192 + c];
    Wd_t[c * O_ + o] = w1 - w2;
    W2_t[c * O_ + o] = w2;
}

// ---------------- K1: 2x2 avg pool -> xd (B,C,N)
__global__ void k_pool(const float* __restrict__ x, float* __restrict__ xd) {
    int idx = blockIdx.x * 256 + threadIdx.x;
    if (idx >= NTOT) return;
    int wd = idx % WDIM; int t = idx / WDIM;
    int hd = t % HD;     int bc = t / HD;
    const float* p = x + ((size_t)bc * H_ + 2 * hd) * W_ + 2 * wd;
    xd[idx] = 0.25f * ((p[0] + p[1]) + (p[W_] + p[W_ + 1]));
}

// ---------------- K2: transpose (B,C,N) -> (B,N,C)
__global__ void k_transpose(const float* __restrict__ xd, float* __restrict__ xt) {
    __shared__ float tile[32][33];
    int bb = blockIdx.z;
    int n0 = blockIdx.x * 32, c0 = blockIdx.y * 32;
    int tx = threadIdx.x, ty = threadIdx.y;   // 32 x 8
    const float* src = xd + (size_t)bb * C_ * NPTS;
    float* dst = xt + (size_t)bb * NPTS * C_;
    #pragma unroll
    for (int j = 0; j < 32; j += 8)
        tile[ty + j][tx] = src[(size_t)(c0 + ty + j) * NPTS + n0 + tx];
    __syncthreads();
    #pragma unroll
    for (int j = 0; j < 32; j += 8)
        dst[(size_t)(n0 + ty + j) * C_ + c0 + tx] = tile[tx][ty + j];
}

// ---------------- K3: sq[b][n] = sum_c xt^2
__global__ void k_sq(const float* __restrict__ xt, float* __restrict__ sq) {
    __shared__ float part[64][4];
    int t = threadIdx.x; int r = t & 63, s = t >> 6;
    int bb = blockIdx.y; int n = blockIdx.x * 64 + r;
    const float* row = xt + ((size_t)bb * NPTS + n) * C_ + s * 48;
    float acc = 0.f;
    #pragma unroll
    for (int c = 0; c < 48; c += 4) {
        float4 v4 = *reinterpret_cast<const float4*>(row + c);
        acc += v4.x * v4.x + v4.y * v4.y + v4.z * v4.z + v4.w * v4.w;
    }
    part[r][s] = acc;
    __syncthreads();
    if (t < 64)
        sq[(size_t)bb * NPTS + blockIdx.x * 64 + t] =
            (part[t][0] + part[t][1]) + (part[t][2] + part[t][3]);
}

// ---------------- K4: u = xt*(W1-W2)^T + b ; v = xt*W2^T   (32 n x 64 o per block)
__global__ __launch_bounds__(256) void k_uv(const float* __restrict__ xt,
                     const float* __restrict__ Wd_t, const float* __restrict__ W2_t,
                     const float* __restrict__ bc,
                     float* __restrict__ u, float* __restrict__ v) {
    __shared__ float xs[32][192];
    int t = threadIdx.x;
    int bb = blockIdx.z, n0 = blockIdx.y * 32;
    int o = blockIdx.x * 64 + (t & 63);
    int w = t >> 6;                      // wave id 0..3
    #pragma unroll
    for (int k = 0; k < 24; ++k) {
        int e = k * 256 + t; int nl = e / 192, c = e % 192;
        xs[nl][c] = xt[((size_t)bb * NPTS + n0 + nl) * C_ + c];
    }
    __syncthreads();
    float au[8], av[8];
    #pragma unroll
    for (int j = 0; j < 8; ++j) { au[j] = 0.f; av[j] = 0.f; }
    for (int c = 0; c < 192; ++c) {
        float w1 = Wd_t[c * O_ + o];
        float w2 = W2_t[c * O_ + o];
        #pragma unroll
        for (int j = 0; j < 8; ++j) {
            float xv = xs[w + 4 * j][c];   // wave-uniform -> LDS broadcast
            au[j] += xv * w1;
            av[j] += xv * w2;
        }
    }
    float bias = bc[o];
    #pragma unroll
    for (int j = 0; j < 8; ++j) {
        int n = n0 + w + 4 * j;
        u[((size_t)bb * NPTS + n) * O_ + o] = au[j] + bias;
        v[((size_t)bb * NPTS + n) * O_ + o] = av[j];
    }
}

// ---------------- K5: kNN tiled GEMM + per-thread top-9.
// Block 128 thr, tile 64 n x 64 m per panel; thread = 4 rows x 8 m (32 acc).
// A/B staged per 48-c chunk into LDS c-major [48][68] (16B-aligned quads).
// Each thread keeps 4 per-row top-9 lists; 8 sub-lists/row merged in-block;
// NCH m-chunk partials merged by k_knnmerge.
#define LESSP(da, ia, db, ib) (((da) < (db)) || (((da) == (db)) && ((ia) < (ib))))

__global__ __launch_bounds__(128, 3) void k_knn(const float* __restrict__ xt,
                                                const float* __restrict__ sq,
                                                float* __restrict__ pd,
                                                int* __restrict__ pi) {
    __shared__ float Ac[48 * 68];        // [c][row], 13056 B
    __shared__ float Bs[48 * 68];        // [c][m]
    int t = threadIdx.x;
    int rq = t & 15, sqi = t >> 4;       // rq: row-quad 0..15, sqi: m-oct 0..7
    int bb = blockIdx.z;
    int n0 = blockIdx.x * 64;
    int q  = blockIdx.y;
    int p0 = q * 10, p1 = (q == 4) ? 49 : q * 10 + 10;
    const float* xb  = xt + (size_t)bb * NPTS * C_;
    const float* sqb = sq + (size_t)bb * NPTS;

    float d9[4][9]; int i9[4][9];
    #pragma unroll
    for (int r = 0; r < 4; ++r)
        #pragma unroll
        for (int k = 0; k < 9; ++k) { d9[r][k] = INFINITY; i9[r][k] = 0x7fffffff; }

    for (int p = p0; p < p1; ++p) {
        int m0 = p * 64;
        float acc[4][8];
        #pragma unroll
        for (int i = 0; i < 4; ++i)
            #pragma unroll
            for (int j = 0; j < 8; ++j) acc[i][j] = 0.f;

        for (int cc = 0; cc < 4; ++cc) {
            __syncthreads();             // previous-chunk readers done before restage
            #pragma unroll
            for (int i = 0; i < 6; ++i) {                 // stage A: 64 rows x 48 c
                int e4 = i * 128 + t; int row = e4 / 12, c4 = e4 % 12;
                float4 v = *reinterpret_cast<const float4*>(
                    xb + (size_t)(n0 + row) * C_ + cc * 48 + c4 * 4);
                Ac[(c4 * 4 + 0) * 68 + row] = v.x;
                Ac[(c4 * 4 + 1) * 68 + row] = v.y;
                Ac[(c4 * 4 + 2) * 68 + row] = v.z;
                Ac[(c4 * 4 + 3) * 68 + row] = v.w;
            }
            #pragma unroll
            for (int i = 0; i < 6; ++i) {                 // stage B: 64 m x 48 c
                int e4 = i * 128 + t; int mm = e4 / 12, c4 = e4 % 12;
                float4 v = *reinterpret_cast<const float4*>(
                    xb + (size_t)(m0 + mm) * C_ + cc * 48 + c4 * 4);
                Bs[(c4 * 4 + 0) * 68 + mm] = v.x;
                Bs[(c4 * 4 + 1) * 68 + mm] = v.y;
                Bs[(c4 * 4 + 2) * 68 + mm] = v.z;
                Bs[(c4 * 4 + 3) * 68 + mm] = v.w;
            }
            __syncthreads();
            #pragma unroll 4
            for (int c = 0; c < 48; ++c) {  // global c ascending: chain matches prior rounds
                float4 av  = *reinterpret_cast<const float4*>(&Ac[c * 68 + rq * 4]);
                float4 bv0 = *reinterpret_cast<const float4*>(&Bs[c * 68 + sqi * 8]);
                float4 bv1 = *reinterpret_cast<const float4*>(&Bs[c * 68 + sqi * 8 + 4]);
                float a[4] = { av.x, av.y, av.z, av.w };
                float b[8] = { bv0.x, bv0.y, bv0.z, bv0.w, bv1.x, bv1.y, bv1.z, bv1.w };
                #pragma unroll
                for (int i = 0; i < 4; ++i)
                    #pragma unroll
                    for (int j = 0; j < 8; ++j)
                        acc[i][j] += a[i] * b[j];         // one v_fmac per (i,j,c)
            }
        }
        // top-9 insert for this panel
        float4 sq0 = *reinterpret_cast<const float4*>(sqb + m0 + sqi * 8);
        float4 sq1 = *reinterpret_cast<const float4*>(sqb + m0 + sqi * 8 + 4);
        float sv[8] = { sq0.x, sq0.y, sq0.z, sq0.w, sq1.x, sq1.y, sq1.z, sq1.w };
        #pragma unroll
        for (int i = 0; i < 4; ++i) {
            #pragma unroll
            for (int j = 0; j < 8; ++j) {
                float d = sv[j] - 2.f * acc[i][j];
                int m = m0 + sqi * 8 + j;
                if (LESSP(d, m, d9[i][8], i9[i][8])) {
                    float pdv = d; int piv = m;
                    #pragma unroll
                    for (int k = 0; k < 9; ++k) {
                        bool cnd = LESSP(pdv, piv, d9[i][k], i9[i][k]);
                        float td = d9[i][k]; int ti = i9[i][k];
                        d9[i][k] = cnd ? pdv : td;  i9[i][k] = cnd ? piv : ti;
                        pdv = cnd ? td : pdv;       piv = cnd ? ti : piv;
                    }
                }
            }
        }
    }

    // in-block merge: per row, 8 sub-lists (one per sqi) -> 9-list; two 32-row rounds
    float* md = Ac;                       // 32*8*9*4 = 9216 B <= 13056
    int*   mi = reinterpret_cast<int*>(Bs);
    #pragma unroll
    for (int half = 0; half < 2; ++half) {
        __syncthreads();
        if ((rq >> 3) == half) {
            int rloc = (rq & 7) * 4;
            #pragma unroll
            for (int r = 0; r < 4; ++r)
                #pragma unroll
                for (int k = 0; k < 9; ++k) {
                    md[((rloc + r) * 8 + sqi) * 9 + k] = d9[r][k];
                    mi[((rloc + r) * 8 + sqi) * 9 + k] = i9[r][k];
                }
        }
        __syncthreads();
        if (t < 32) {
            int row = half * 32 + t;
            int pp[8];
            #pragma unroll
            for (int s2 = 0; s2 < 8; ++s2) pp[s2] = 0;
            size_t base = (((size_t)bb * NPTS + n0 + row) * NCH + q) * 9;
            for (int k = 0; k < 9; ++k) {
                float bd = INFINITY; int bi = 0x7fffffff; int bs = -1;
                #pragma unroll
                for (int s2 = 0; s2 < 8; ++s2) {
                    float dv = md[(t * 8 + s2) * 9 + pp[s2]];
                    int   iv = mi[(t * 8 + s2) * 9 + pp[s2]];
                    if (LESSP(dv, iv, bd, bi)) { bd = dv; bi = iv; bs = s2; }
                }
                pd[base + k] = bd;
                pi[base + k] = bi;
                #pragma unroll
                for (int s2 = 0; s2 < 8; ++s2) if (s2 == bs) pp[s2]++;
            }
        }
    }
}

// ---------------- K5b: merge NCH per-chunk top-9 lists -> global top-9 indices
__global__ void k_knnmerge(const float* __restrict__ pd, const int* __restrict__ pi,
                           int* __restrict__ nn) {
    int row = blockIdx.x * 256 + threadIdx.x;
    if (row >= B_ * NPTS) return;
    const float* d0 = pd + (size_t)row * (NCH * 9);
    const int*   i0 = pi + (size_t)row * (NCH * 9);
    int p[NCH];
    #pragma unroll
    for (int qq = 0; qq < NCH; ++qq) p[qq] = 0;
    for (int k = 0; k < 9; ++k) {
        float bd = INFINITY; int bi = 0x7fffffff; int bq = -1;
        #pragma unroll
        for (int qq = 0; qq < NCH; ++qq) {
            float dv = d0[qq * 9 + p[qq]];
            int   iv = i0[qq * 9 + p[qq]];
            if (LESSP(dv, iv, bd, bi)) { bd = dv; bi = iv; bq = qq; }
        }
        nn[(size_t)row * KNN + k] = bi;
        #pragma unroll
        for (int qq = 0; qq < NCH; ++qq) if (qq == bq) p[qq]++;
    }
}

// ---------------- K6: h = u[n]+v[m], gelu, max over k; write (B,O,N) via LDS transpose
__global__ __launch_bounds__(256) void k_gmax(const float* __restrict__ u,
                      const float* __restrict__ v, const int* __restrict__ nn,
                      float* __restrict__ os) {
    __shared__ float st[192 * 33];
    __shared__ int   sidx[32 * KNN];
    int t = threadIdx.x;
    int bb = blockIdx.y, n0 = blockIdx.x * 32;
    for (int e = t; e < 32 * KNN; e += 256)
        sidx[e] = nn[((size_t)bb * NPTS + n0) * KNN + e];
    __syncthreads();
    const float* vb = v + (size_t)bb * NPTS * O_;
    #pragma unroll 2
    for (int wv = 0; wv < 24; ++wv) {
        int e = wv * 256 + t; int nl = e / 192, o = e % 192;
        float uo = u[((size_t)bb * NPTS + n0 + nl) * O_ + o];
        float best = -INFINITY;
        #pragma unroll
        for (int k = 0; k < KNN; ++k) {
            int m = sidx[nl * KNN + k];
            float h = uo + vb[(size_t)m * O_ + o];
            float gel = 0.5f * h * (1.0f + erff(h * 0.70710678118654752f));
            best = fmaxf(best, gel);
        }
        st[o * 33 + nl] = best;
    }
    __syncthreads();
    float* ob = os + (size_t)bb * O_ * NPTS;
    #pragma unroll 2
    for (int wv = 0; wv < 24; ++wv) {
        int e = wv * 256 + t; int o = e / 32, nl = e % 32;
        ob[(size_t)o * NPTS + n0 + nl] = st[o * 33 + nl];
    }
}

// ---------------- K7: 2x bilinear upsample 56->112 (half-pixel, edge-renormalized)
__global__ void k_upsample(const float* __restrict__ os, float* __restrict__ out) {
    int idx = blockIdx.x * 256 + threadIdx.x;
    if (idx >= OUT_TOT) return;
    int j = idx % W_; int t2 = idx / W_;
    int i = t2 % H_;  int bo = t2 / H_;
    int i0, i1; float wi0, wi1;
    if (i & 1) { i0 = i >> 1; i1 = i0 + 1; wi0 = 0.75f; wi1 = 0.25f; }
    else       { i1 = i >> 1; i0 = i1 - 1; wi0 = 0.25f; wi1 = 0.75f; }
    i0 = max(i0, 0); i1 = min(i1, HD - 1);
    int j0, j1; float wj0, wj1;
    if (j & 1) { j0 = j >> 1; j1 = j0 + 1; wj0 = 0.75f; wj1 = 0.25f; }
    else       { j1 = j >> 1; j0 = j1 - 1; wj0 = 0.25f; wj1 = 0.75f; }
    j0 = max(j0, 0); j1 = min(j1, WDIM - 1);
    const float* base = os + (size_t)bo * NPTS;
    float v00 = base[i0 * WDIM + j0], v01 = base[i0 * WDIM + j1];
    float v10 = base[i1 * WDIM + j0], v11 = base[i1 * WDIM + j1];
    out[idx] = wi0 * (wj0 * v00 + wj1 * v01) + wi1 * (wj0 * v10 + wj1 * v11);
}

extern "C" void kernel_launch(void* const* d_in, const int* in_sizes, int n_in,
                              void* d_out, int out_size, void* d_ws, size_t ws_size,
                              hipStream_t stream) {
    const float* x  = (const float*)d_in[0];
    const float* Wc = (const float*)d_in[1];
    const float* bc = (const float*)d_in[2];
    float* out = (float*)d_out;

    char* ws = (char*)d_ws;
    const size_t SZ = (size_t)NTOT * 4;        // 19,267,584 B
    float* xd = (float*)(ws);                  // dead after k_transpose -> reused for pd/pi, then os
    float* xt = (float*)(ws + SZ);
    float* u  = (float*)(ws + 2 * SZ);
    float* v  = (float*)(ws + 3 * SZ);
    float* sq = (float*)(ws + 4 * SZ);                       // 100,352 B
    float* Wd = (float*)(ws + 4 * SZ + 100352);              // 147,456 B
    float* W2 = (float*)(ws + 4 * SZ + 100352 + 147456);     // 147,456 B
    int*   nn = (int*)  (ws + 4 * SZ + 100352 + 2 * 147456); // 903,168 B
    // partial top-9 lists in the dead xd region: 25088*45*4 = 4,515,840 B each
    float* pd = (float*)(ws);
    int*   pi = (int*)  (ws + 4515840);
    float* os = xd;                            // reuse: pd/pi dead after k_knnmerge

    k_wprep<<<dim3((C_ * O_ + 255) / 256), 256, 0, stream>>>(Wc, Wd, W2);
    k_pool<<<dim3(NTOT / 256), 256, 0, stream>>>(x, xd);
    k_transpose<<<dim3(NPTS / 32, C_ / 32, B_), dim3(32, 8), 0, stream>>>(xd, xt);
    k_sq<<<dim3(NPTS / 64, B_), 256, 0, stream>>>(xt, sq);
    k_uv<<<dim3(O_ / 64, NPTS / 32, B_), 256, 0, stream>>>(xt, Wd, W2, bc, u, v);
    k_knn<<<dim3(49, NCH, B_), 128, 0, stream>>>(xt, sq, pd, pi);
    k_knnmerge<<<dim3((B_ * NPTS + 255) / 256), 256, 0, stream>>>(pd, pi, nn);
    k_gmax<<<dim3(NPTS / 32, B_), 256, 0, stream>>>(u, v, nn, os);
    k_upsample<<<dim3(OUT_TOT / 256), 256, 0, stream>>>(os, out);
}

// Round 12
// 1333.779 us; speedup vs baseline: 1.9086x; 1.1960x over previous
//
#include <hip/hip_runtime.h>
#include <hip/hip_bf16.h>
#include <math.h>

#define B_    8
#define C_    192
#define H_    112
#define W_    112
#define HD    56
#define WDIM  56
#define NPTS  3136      // 56*56 = 49*64
#define KNN   9
#define O_    192
#define NTOT  (B_*C_*NPTS)          // 4,816,896 pooled elems
#define OUT_TOT (B_*O_*H_*W_)       // 19,267,584
#define NCH   5         // m-chunks in k_knn grid (panels: 10,10,10,10,9 of 64 m)

// ---------------- K0: W prep: Wd_t[c][o] = W[o][c]-W[o][c+192]; W2_t[c][o]=W[o][c+192]
__global__ void k_wprep(const float* __restrict__ Wc,
                        float* __restrict__ Wd_t, float* __restrict__ W2_t) {
    int idx = blockIdx.x * 256 + threadIdx.x;
    if (idx >= C_ * O_) return;
    int o = idx / C_, c = idx % C_;          // read coalesced over c
    float w1 = Wc[o * 384 + c];
    float w2 = Wc[o * 384 + 192 + c];
    Wd_t[c * O_ + o] = w1 - w2;
    W2_t[c * O_ + o] = w2;
}

// ---------------- K1: 2x2 avg pool -> xd (B,C,N)
__global__ void k_pool(const float* __restrict__ x, float* __restrict__ xd) {
    int idx = blockIdx.x * 256 + threadIdx.x;
    if (idx >= NTOT) return;
    int wd = idx % WDIM; int t = idx / WDIM;
    int hd = t % HD;     int bc = t / HD;
    const float* p = x + ((size_t)bc * H_ + 2 * hd) * W_ + 2 * wd;
    xd[idx] = 0.25f * ((p[0] + p[1]) + (p[W_] + p[W_ + 1]));
}

// ---------------- K2: transpose (B,C,N) -> (B,N,C)  (xt feeds k_sq / k_uv)
__global__ void k_transpose(const float* __restrict__ xd, float* __restrict__ xt) {
    __shared__ float tile[32][33];
    int bb = blockIdx.z;
    int n0 = blockIdx.x * 32, c0 = blockIdx.y * 32;
    int tx = threadIdx.x, ty = threadIdx.y;   // 32 x 8
    const float* src = xd + (size_t)bb * C_ * NPTS;
    float* dst = xt + (size_t)bb * NPTS * C_;
    #pragma unroll
    for (int j = 0; j < 32; j += 8)
        tile[ty + j][tx] = src[(size_t)(c0 + ty + j) * NPTS + n0 + tx];
    __syncthreads();
    #pragma unroll
    for (int j = 0; j < 32; j += 8)
        dst[(size_t)(n0 + ty + j) * C_ + c0 + tx] = tile[tx][ty + j];
}

// ---------------- K3: sq[b][n] = sum_c xt^2
__global__ void k_sq(const float* __restrict__ xt, float* __restrict__ sq) {
    __shared__ float part[64][4];
    int t = threadIdx.x; int r = t & 63, s = t >> 6;
    int bb = blockIdx.y; int n = blockIdx.x * 64 + r;
    const float* row = xt + ((size_t)bb * NPTS + n) * C_ + s * 48;
    float acc = 0.f;
    #pragma unroll
    for (int c = 0; c < 48; c += 4) {
        float4 v4 = *reinterpret_cast<const float4*>(row + c);
        acc += v4.x * v4.x + v4.y * v4.y + v4.z * v4.z + v4.w * v4.w;
    }
    part[r][s] = acc;
    __syncthreads();
    if (t < 64)
        sq[(size_t)bb * NPTS + blockIdx.x * 64 + t] =
            (part[t][0] + part[t][1]) + (part[t][2] + part[t][3]);
}

// ---------------- K4: u = xt*(W1-W2)^T + b ; v = xt*W2^T   (32 n x 64 o per block)
__global__ __launch_bounds__(256) void k_uv(const float* __restrict__ xt,
                     const float* __restrict__ Wd_t, const float* __restrict__ W2_t,
                     const float* __restrict__ bc,
                     float* __restrict__ u, float* __restrict__ v) {
    __shared__ float xs[32][192];
    int t = threadIdx.x;
    int bb = blockIdx.z, n0 = blockIdx.y * 32;
    int o = blockIdx.x * 64 + (t & 63);
    int w = t >> 6;                      // wave id 0..3
    #pragma unroll
    for (int k = 0; k < 24; ++k) {
        int e = k * 256 + t; int nl = e / 192, c = e % 192;
        xs[nl][c] = xt[((size_t)bb * NPTS + n0 + nl) * C_ + c];
    }
    __syncthreads();
    float au[8], av[8];
    #pragma unroll
    for (int j = 0; j < 8; ++j) { au[j] = 0.f; av[j] = 0.f; }
    for (int c = 0; c < 192; ++c) {
        float w1 = Wd_t[c * O_ + o];
        float w2 = W2_t[c * O_ + o];
        #pragma unroll
        for (int j = 0; j < 8; ++j) {
            float xv = xs[w + 4 * j][c];   // wave-uniform -> LDS broadcast
            au[j] += xv * w1;
            av[j] += xv * w2;
        }
    }
    float bias = bc[o];
    #pragma unroll
    for (int j = 0; j < 8; ++j) {
        int n = n0 + w + 4 * j;
        u[((size_t)bb * NPTS + n) * O_ + o] = au[j] + bias;
        v[((size_t)bb * NPTS + n) * O_ + o] = av[j];
    }
}

// ---------------- K5: kNN tiled GEMM + per-thread top-9, staged from xd (c-major).
// Block 128 thr, tile 64 n x 64 m per panel; thread = 4 rows x 8 m (32 acc).
// Staging: LDS [c][n]/[c][m] built with lane-contiguous b128 writes (conflict-free),
// reading xd (B,C,N) directly -> no in-thread transpose.
#define LESSP(da, ia, db, ib) (((da) < (db)) || (((da) == (db)) && ((ia) < (ib))))

__global__ __launch_bounds__(128, 3) void k_knn(const float* __restrict__ xd,
                                                const float* __restrict__ sq,
                                                float* __restrict__ pd,
                                                int* __restrict__ pi) {
    __shared__ float Ac[48 * 68];        // [c][row], stride 68 (272 B, 16B-aligned)
    __shared__ float Bs[48 * 68];        // [c][m]
    int t = threadIdx.x;
    int rq = t & 15, sqi = t >> 4;       // rq: row-quad 0..15, sqi: m-oct 0..7
    int bb = blockIdx.z;
    int n0 = blockIdx.x * 64;
    int q  = blockIdx.y;
    int p0 = q * 10, p1 = (q == 4) ? 49 : q * 10 + 10;
    const float* xdb = xd + (size_t)bb * C_ * NPTS;   // [c][n] c-major
    const float* sqb = sq + (size_t)bb * NPTS;

    float d9[4][9]; int i9[4][9];
    #pragma unroll
    for (int r = 0; r < 4; ++r)
        #pragma unroll
        for (int k = 0; k < 9; ++k) { d9[r][k] = INFINITY; i9[r][k] = 0x7fffffff; }

    for (int p = p0; p < p1; ++p) {
        int m0 = p * 64;
        float acc[4][8];
        #pragma unroll
        for (int i = 0; i < 4; ++i)
            #pragma unroll
            for (int j = 0; j < 8; ++j) acc[i][j] = 0.f;

        for (int cc = 0; cc < 4; ++cc) {
            __syncthreads();             // previous-chunk readers done before restage
            #pragma unroll
            for (int i = 0; i < 6; ++i) {                 // stage A: 48 c x 64 n
                int e = i * 128 + t; int c_loc = e >> 4, nq = e & 15;
                float4 vv = *reinterpret_cast<const float4*>(
                    xdb + (size_t)(cc * 48 + c_loc) * NPTS + n0 + nq * 4);
                *reinterpret_cast<float4*>(&Ac[c_loc * 68 + nq * 4]) = vv;
            }
            #pragma unroll
            for (int i = 0; i < 6; ++i) {                 // stage B: 48 c x 64 m
                int e = i * 128 + t; int c_loc = e >> 4, mq = e & 15;
                float4 vv = *reinterpret_cast<const float4*>(
                    xdb + (size_t)(cc * 48 + c_loc) * NPTS + m0 + mq * 4);
                *reinterpret_cast<float4*>(&Bs[c_loc * 68 + mq * 4]) = vv;
            }
            __syncthreads();
            #pragma unroll 4
            for (int c = 0; c < 48; ++c) {  // global c ascending: chain matches prior rounds
                float4 av  = *reinterpret_cast<const float4*>(&Ac[c * 68 + rq * 4]);
                float4 bv0 = *reinterpret_cast<const float4*>(&Bs[c * 68 + sqi * 8]);
                float4 bv1 = *reinterpret_cast<const float4*>(&Bs[c * 68 + sqi * 8 + 4]);
                float a[4] = { av.x, av.y, av.z, av.w };
                float b[8] = { bv0.x, bv0.y, bv0.z, bv0.w, bv1.x, bv1.y, bv1.z, bv1.w };
                #pragma unroll
                for (int i = 0; i < 4; ++i)
                    #pragma unroll
                    for (int j = 0; j < 8; ++j)
                        acc[i][j] += a[i] * b[j];         // one v_fmac per (i,j,c)
            }
        }
        // top-9 insert for this panel
        float4 sq0 = *reinterpret_cast<const float4*>(sqb + m0 + sqi * 8);
        float4 sq1 = *reinterpret_cast<const float4*>(sqb + m0 + sqi * 8 + 4);
        float sv[8] = { sq0.x, sq0.y, sq0.z, sq0.w, sq1.x, sq1.y, sq1.z, sq1.w };
        #pragma unroll
        for (int i = 0; i < 4; ++i) {
            #pragma unroll
            for (int j = 0; j < 8; ++j) {
                float d = sv[j] - 2.f * acc[i][j];
                int m = m0 + sqi * 8 + j;
                if (LESSP(d, m, d9[i][8], i9[i][8])) {
                    float pdv = d; int piv = m;
                    #pragma unroll
                    for (int k = 0; k < 9; ++k) {
                        bool cnd = LESSP(pdv, piv, d9[i][k], i9[i][k]);
                        float td = d9[i][k]; int ti = i9[i][k];
                        d9[i][k] = cnd ? pdv : td;  i9[i][k] = cnd ? piv : ti;
                        pdv = cnd ? td : pdv;       piv = cnd ? ti : piv;
                    }
                }
            }
        }
    }

    // in-block merge: per row, 8 sub-lists (one per sqi) -> 9-list; two 32-row rounds
    float* md = Ac;                       // 32*8*9*4 = 9216 B <= 13056
    int*   mi = reinterpret_cast<int*>(Bs);
    #pragma unroll
    for (int half = 0; half < 2; ++half) {
        __syncthreads();
        if ((rq >> 3) == half) {
            int rloc = (rq & 7) * 4;
            #pragma unroll
            for (int r = 0; r < 4; ++r)
                #pragma unroll
                for (int k = 0; k < 9; ++k) {
                    md[((rloc + r) * 8 + sqi) * 9 + k] = d9[r][k];
                    mi[((rloc + r) * 8 + sqi) * 9 + k] = i9[r][k];
                }
        }
        __syncthreads();
        if (t < 32) {
            int row = half * 32 + t;
            int pp[8];
            #pragma unroll
            for (int s2 = 0; s2 < 8; ++s2) pp[s2] = 0;
            size_t base = (((size_t)bb * NPTS + n0 + row) * NCH + q) * 9;
            for (int k = 0; k < 9; ++k) {
                float bd = INFINITY; int bi = 0x7fffffff; int bs = -1;
                #pragma unroll
                for (int s2 = 0; s2 < 8; ++s2) {
                    float dv = md[(t * 8 + s2) * 9 + pp[s2]];
                    int   iv = mi[(t * 8 + s2) * 9 + pp[s2]];
                    if (LESSP(dv, iv, bd, bi)) { bd = dv; bi = iv; bs = s2; }
                }
                pd[base + k] = bd;
                pi[base + k] = bi;
                #pragma unroll
                for (int s2 = 0; s2 < 8; ++s2) if (s2 == bs) pp[s2]++;
            }
        }
    }
}

// ---------------- K5b: merge NCH per-chunk top-9 lists -> global top-9 indices
__global__ void k_knnmerge(const float* __restrict__ pd, const int* __restrict__ pi,
                           int* __restrict__ nn) {
    int row = blockIdx.x * 256 + threadIdx.x;
    if (row >= B_ * NPTS) return;
    const float* d0 = pd + (size_t)row * (NCH * 9);
    const int*   i0 = pi + (size_t)row * (NCH * 9);
    int p[NCH];
    #pragma unroll
    for (int qq = 0; qq < NCH; ++qq) p[qq] = 0;
    for (int k = 0; k < 9; ++k) {
        float bd = INFINITY; int bi = 0x7fffffff; int bq = -1;
        #pragma unroll
        for (int qq = 0; qq < NCH; ++qq) {
            float dv = d0[qq * 9 + p[qq]];
            int   iv = i0[qq * 9 + p[qq]];
            if (LESSP(dv, iv, bd, bi)) { bd = dv; bi = iv; bq = qq; }
        }
        nn[(size_t)row * KNN + k] = bi;
        #pragma unroll
        for (int qq = 0; qq < NCH; ++qq) if (qq == bq) p[qq]++;
    }
}

// ---------------- K6: h = u[n]+v[m], gelu, max over k; write (B,O,N) via LDS transpose
__global__ __launch_bounds__(256) void k_gmax(const float* __restrict__ u,
                      const float* __restrict__ v, const int* __restrict__ nn,
                      float* __restrict__ os) {
    __shared__ float st[192 * 33];
    __shared__ int   sidx[32 * KNN];
    int t = threadIdx.x;
    int bb = blockIdx.y, n0 = blockIdx.x * 32;
    for (int e = t; e < 32 * KNN; e += 256)
        sidx[e] = nn[((size_t)bb * NPTS + n0) * KNN + e];
    __syncthreads();
    const float* vb = v + (size_t)bb * NPTS * O_;
    #pragma unroll 2
    for (int wv = 0; wv < 24; ++wv) {
        int e = wv * 256 + t; int nl = e / 192, o = e % 192;
        float uo = u[((size_t)bb * NPTS + n0 + nl) * O_ + o];
        float best = -INFINITY;
        #pragma unroll
        for (int k = 0; k < KNN; ++k) {
            int m = sidx[nl * KNN + k];
            float h = uo + vb[(size_t)m * O_ + o];
            float gel = 0.5f * h * (1.0f + erff(h * 0.70710678118654752f));
            best = fmaxf(best, gel);
        }
        st[o * 33 + nl] = best;
    }
    __syncthreads();
    float* ob = os + (size_t)bb * O_ * NPTS;
    #pragma unroll 2
    for (int wv = 0; wv < 24; ++wv) {
        int e = wv * 256 + t; int o = e / 32, nl = e % 32;
        ob[(size_t)o * NPTS + n0 + nl] = st[o * 33 + nl];
    }
}

// ---------------- K7: 2x bilinear upsample 56->112 (half-pixel, edge-renormalized)
__global__ void k_upsample(const float* __restrict__ os, float* __restrict__ out) {
    int idx = blockIdx.x * 256 + threadIdx.x;
    if (idx >= OUT_TOT) return;
    int j = idx % W_; int t2 = idx / W_;
    int i = t2 % H_;  int bo = t2 / H_;
    int i0, i1; float wi0, wi1;
    if (i & 1) { i0 = i >> 1; i1 = i0 + 1; wi0 = 0.75f; wi1 = 0.25f; }
    else       { i1 = i >> 1; i0 = i1 - 1; wi0 = 0.25f; wi1 = 0.75f; }
    i0 = max(i0, 0); i1 = min(i1, HD - 1);
    int j0, j1; float wj0, wj1;
    if (j & 1) { j0 = j >> 1; j1 = j0 + 1; wj0 = 0.75f; wj1 = 0.25f; }
    else       { j1 = j >> 1; j0 = j1 - 1; wj0 = 0.25f; wj1 = 0.75f; }
    j0 = max(j0, 0); j1 = min(j1, WDIM - 1);
    const float* base = os + (size_t)bo * NPTS;
    float v00 = base[i0 * WDIM + j0], v01 = base[i0 * WDIM + j1];
    float v10 = base[i1 * WDIM + j0], v11 = base[i1 * WDIM + j1];
    out[idx] = wi0 * (wj0 * v00 + wj1 * v01) + wi1 * (wj0 * v10 + wj1 * v11);
}

extern "C" void kernel_launch(void* const* d_in, const int* in_sizes, int n_in,
                              void* d_out, int out_size, void* d_ws, size_t ws_size,
                              hipStream_t stream) {
    const float* x  = (const float*)d_in[0];
    const float* Wc = (const float*)d_in[1];
    const float* bc = (const float*)d_in[2];
    float* out = (float*)d_out;

    char* ws = (char*)d_ws;
    const size_t SZ = (size_t)NTOT * 4;        // 19,267,584 B
    float* xd = (float*)(ws);                  // live through k_knn; then reused as os
    float* xt = (float*)(ws + SZ);             // live through k_uv; then reused as pd/pi
    float* u  = (float*)(ws + 2 * SZ);
    float* v  = (float*)(ws + 3 * SZ);
    float* sq = (float*)(ws + 4 * SZ);                       // 100,352 B
    float* Wd = (float*)(ws + 4 * SZ + 100352);              // 147,456 B
    float* W2 = (float*)(ws + 4 * SZ + 100352 + 147456);     // 147,456 B
    int*   nn = (int*)  (ws + 4 * SZ + 100352 + 2 * 147456); // 903,168 B
    // partial top-9 lists in the dead xt region: 25088*45*4 = 4,515,840 B each
    float* pd = (float*)(ws + SZ);
    int*   pi = (int*)  (ws + SZ + 4515840);
    float* os = xd;                            // k_gmax writes after k_knn's last xd read

    k_wprep<<<dim3((C_ * O_ + 255) / 256), 256, 0, stream>>>(Wc, Wd, W2);
    k_pool<<<dim3(NTOT / 256), 256, 0, stream>>>(x, xd);
    k_transpose<<<dim3(NPTS / 32, C_ / 32, B_), dim3(32, 8), 0, stream>>>(xd, xt);
    k_sq<<<dim3(NPTS / 64, B_), 256, 0, stream>>>(xt, sq);
    k_uv<<<dim3(O_ / 64, NPTS / 32, B_), 256, 0, stream>>>(xt, Wd, W2, bc, u, v);
    k_knn<<<dim3(49, NCH, B_), 128, 0, stream>>>(xd, sq, pd, pi);
    k_knnmerge<<<dim3((B_ * NPTS + 255) / 256), 256, 0, stream>>>(pd, pi, nn);
    k_gmax<<<dim3(NPTS / 32, B_), 256, 0, stream>>>(u, v, nn, os);
    k_upsample<<<dim3(OUT_TOT / 256), 256, 0, stream>>>(os, out);
}